// Round 8
// baseline (61.323 us; speedup 1.0000x reference)
//
#include <hip/hip_runtime.h>

#define NSCENE 64
#define NPTS   16384
#define SIN    256
#define SH     128
#define SOUT   128
#define XSLOTS 18432              // >= NPTS + 64*31, multiple of 32

// ---- workspace layout (bytes) ----
#define WS_PARTIAL 0                          // 64*64 int
#define WS_OFFSETS 16384                      // 65 int (padded scene offsets)
#define WS_SLOTMAP 17408                      // XSLOTS ints = 73728 B
#define WS_WBF16   (17408 + 73728)            // 91136: 5,242,880 shorts (fragment-ordered)
#define WS_XG      (WS_WBF16 + 10485760)      // 10,576,896: 2 * XR_ELEMS shorts
#define W0_ELEMS   (NSCENE*SH*SIN)            // 2,097,152
#define W1_ELEMS   (NSCENE*SOUT*SH)           // 1,048,576
#define W2_ELEMS   (NSCENE*SOUT*SIN)          // 2,097,152
#define WTOT       (W0_ELEMS+W1_ELEMS+W2_ELEMS)
#define CONV_BLOCKS (WTOT/2048)
#define XR_ELEMS   (XSLOTS * 256)             // 4,718,592 shorts per variant
// weight fragment order per scene region: [colgrp16][ks][lane][8]
//   L0/L2: cg<<12 | ks<<9 | lane<<3 (8 ks)    L1: cg<<11 | ks<<9 | lane<<3 (4 ks)
// x fragment order: [tile16][ks][lane][8]: lane l = (slot&15) + 16*h4 holds
//   x[n][ks*32 + h4*8 .. +8]  (A-fragment layout for mfma 16x16x32)

typedef __attribute__((ext_vector_type(8))) short bf16x8;
typedef __attribute__((ext_vector_type(4))) float f32x4;

__device__ __forceinline__ short f2bf(float f) {
  unsigned int u = __float_as_uint(f);
  unsigned int r = (u + 0x7FFFu + ((u >> 16) & 1u)) >> 16;
  return (short)(r & 0xFFFFu);
}

__device__ __forceinline__ bf16x8 cvt8(const float* src) {
  float4 u0 = *reinterpret_cast<const float4*>(src);
  float4 u1 = *reinterpret_cast<const float4*>(src + 4);
  return (bf16x8){f2bf(u0.x), f2bf(u0.y), f2bf(u0.z), f2bf(u0.w),
                  f2bf(u1.x), f2bf(u1.y), f2bf(u1.z), f2bf(u1.w)};
}

// ---------------- K1: partial histograms + fragment-ordered weight conversion ----------------

__global__ __launch_bounds__(256) void prep_kernel(
    const int* __restrict__ bidx,
    const float* __restrict__ kls0, const float* __restrict__ kls1,
    const float* __restrict__ kls2,
    int* __restrict__ partial, short* __restrict__ wb)
{
  int b = blockIdx.x;
  int tid = threadIdx.x;
  if (b < 64) {
    __shared__ int lh[NSCENE];
    if (tid < NSCENE) lh[tid] = 0;
    __syncthreads();
    atomicAdd(&lh[bidx[b * 256 + tid]], 1);
    __syncthreads();
    if (tid < NSCENE) partial[b * 64 + tid] = lh[tid];
  } else {
    int e = ((b - 64) * 256 + tid) * 8;
    if (e < WTOT) {
      const float* src;
      if (e < W0_ELEMS) {
        int s = e >> 15, r = e & 32767;
        int cg = r >> 12, ks = (r >> 9) & 7, l = (r >> 3) & 63;
        int row = cg * 16 + (l & 15), k = ks * 32 + (l >> 4) * 8;
        src = kls0 + ((size_t)s << 15) + row * SIN + k;
      } else if (e < W0_ELEMS + W1_ELEMS) {
        int e1 = e - W0_ELEMS;
        int s = e1 >> 14, r = e1 & 16383;
        int cg = r >> 11, ks = (r >> 9) & 3, l = (r >> 3) & 63;
        int row = cg * 16 + (l & 15), k = ks * 32 + (l >> 4) * 8;
        src = kls1 + ((size_t)s << 14) + row * SH + k;
      } else {
        int e2 = e - W0_ELEMS - W1_ELEMS;
        int s = e2 >> 15, r = e2 & 32767;
        int cg = r >> 12, ks = (r >> 9) & 7, l = (r >> 3) & 63;
        int row = cg * 16 + (l & 15), k = ks * 32 + (l >> 4) * 8;
        src = kls2 + ((size_t)s << 15) + row * SIN + k;
      }
      *reinterpret_cast<bf16x8*>(wb + e) = cvt8(src);
    }
  }
}

// ---------------- K2: scan (padded to 32) + scatter into slotmap ----------------

__global__ __launch_bounds__(256) void scatter_kernel(
    const int* __restrict__ bidx, const int* __restrict__ partial,
    int* __restrict__ offsets, int* __restrict__ slotmap)
{
  __shared__ int cur[NSCENE];
  __shared__ int scnt[NSCENE], soff[NSCENE];
  int b = blockIdx.x;
  int tid = threadIdx.x;
  if (tid < 64) {
    int s = tid;
    int colpre = 0, total = 0;
    for (int bb = 0; bb < 64; ++bb) {
      int v = partial[bb * 64 + s];
      if (bb < b) colpre += v;
      total += v;
    }
    int p = (total + 31) & ~31;       // padded scene size
    int v = p;
    for (int off = 1; off < 64; off <<= 1) {
      int t = __shfl_up(v, off);
      if (s >= off) v += t;
    }
    int offp = v - p;                 // exclusive padded offset
    cur[s]  = offp + colpre;
    scnt[s] = total;
    soff[s] = offp;
    if (b == 0) {
      offsets[s] = offp;
      if (s == 63) offsets[64] = v;   // total padded slots
    }
  }
  __syncthreads();
  if (b == 0 && tid < 64) {           // fill pad slots with -1
    int st = soff[tid] + scnt[tid];
    int en = soff[tid] + ((scnt[tid] + 31) & ~31);
    for (int i = st; i < en; ++i) slotmap[i] = -1;
  }
  int n = b * 256 + tid;
  int s2 = bidx[n];
  int pos = atomicAdd(&cur[s2], 1);
  slotmap[pos] = n;
}

// ---------------- K3: x gather + bf16 convert into A-fragment order ----------------
// grid 576 x 256: block handles 32 slots; 8 threads per slot (one per ks chunk).

__global__ __launch_bounds__(256) void xgather_kernel(
    const float* __restrict__ x, const int* __restrict__ slotmap,
    short* __restrict__ xg)
{
  int slot = blockIdx.x * 32 + (threadIdx.x >> 3);
  int ks   = threadIdx.x & 7;
  int n = slotmap[slot];
  if ((unsigned)n >= (unsigned)NPTS) return;   // pad (-1) or stale slot
  const float* px = x + (size_t)n * SIN + ks * 32;
  size_t fo = ((size_t)(slot >> 4) << 12) + (ks << 9) + ((slot & 15) << 3);
  short* xr = xg + fo;
  short* xp = xg + XR_ELEMS + fo;
#pragma unroll
  for (int h4 = 0; h4 < 4; ++h4) {
    float4 u0 = *reinterpret_cast<const float4*>(px + h4 * 8);
    float4 u1 = *reinterpret_cast<const float4*>(px + h4 * 8 + 4);
    bf16x8 vp = (bf16x8){f2bf(u0.x), f2bf(u0.y), f2bf(u0.z), f2bf(u0.w),
                         f2bf(u1.x), f2bf(u1.y), f2bf(u1.z), f2bf(u1.w)};
    bf16x8 vr = (bf16x8){f2bf(fmaxf(u0.x, 0.f)), f2bf(fmaxf(u0.y, 0.f)),
                         f2bf(fmaxf(u0.z, 0.f)), f2bf(fmaxf(u0.w, 0.f)),
                         f2bf(fmaxf(u1.x, 0.f)), f2bf(fmaxf(u1.y, 0.f)),
                         f2bf(fmaxf(u1.z, 0.f)), f2bf(fmaxf(u1.w, 0.f))};
    *reinterpret_cast<bf16x8*>(xp + h4 * 128) = vp;
    *reinterpret_cast<bf16x8*>(xr + h4 * 128) = vr;
  }
}

// ---------------- K4: fused GEMM — 1-hop loads, no staging, no A-side f2bf ----------------
// grid 768: bid = tslot*64 + s (scene pinned to XCD bid%8 == s%8).
// 256 threads = 4 waves; wave w owns cols [w*32, w*32+32) (2 frags), tile = 32 points.

__global__ __launch_bounds__(256, 4) void fused_kernel(
    const float* __restrict__ bias0, const float* __restrict__ bias1,
    const int* __restrict__ offsets, const int* __restrict__ slotmap,
    const short* __restrict__ wb, const short* __restrict__ xg,
    float* __restrict__ out)
{
  __shared__ __align__(16) short snet[32][SH + 8];

  const int s     = blockIdx.x & 63;
  const int tslot = blockIdx.x >> 6;
  const int base  = offsets[s];
  const int cntp  = offsets[s + 1] - base;     // padded, multiple of 32
  const int tid   = threadIdx.x;
  const int lane  = tid & 63;
  const int w     = tid >> 6;                  // 0..3
  const int l15   = lane & 15;
  const int lh4   = lane >> 4;

  const short* wb0 = wb + ((size_t)s << 15);
  const short* wb1 = wb + W0_ELEMS + ((size_t)s << 14);
  const short* wb2 = wb + W0_ELEMS + W1_ELEMS + ((size_t)s << 15);
  const short* xr  = xg;
  const short* xp  = xg + XR_ELEMS;

  float bv0[2], bv1[2];
#pragma unroll
  for (int nt = 0; nt < 2; ++nt) {
    int col = (2 * w + nt) * 16 + l15;
    bv0[nt] = bias0[(size_t)s * SH + col];
    bv1[nt] = bias1[(size_t)s * SOUT + col];
  }

  for (int t = tslot; t * 32 < cntp; t += 12) {
    const int p0 = base + t * 32;                       // 32-aligned
    int ptv = (lane < 32) ? slotmap[p0 + lane] : -1;
    const size_t xo = ((size_t)(p0 >> 4) << 12) + (lane << 3);
    __syncthreads();   // protect snet reuse across tile iterations

    f32x4 acc0[2][2], acc1[2][2];                       // [mt][nt]
#pragma unroll
    for (int mt = 0; mt < 2; ++mt)
#pragma unroll
      for (int nt = 0; nt < 2; ++nt) {
        acc0[mt][nt] = (f32x4){bv0[nt], bv0[nt], bv0[nt], bv0[nt]};
        acc1[mt][nt] = (f32x4){bv1[nt], bv1[nt], bv1[nt], bv1[nt]};
      }

    // ---- layers 0 + 2: all operands are single coalesced dwordx4 loads ----
#pragma unroll
    for (int ks = 0; ks < 8; ++ks) {
      bf16x8 aR[2], aP[2], b0f[2], b2f[2];
#pragma unroll
      for (int mt = 0; mt < 2; ++mt) {
        aR[mt] = *reinterpret_cast<const bf16x8*>(xr + xo + ((size_t)mt << 12) + (ks << 9));
        aP[mt] = *reinterpret_cast<const bf16x8*>(xp + xo + ((size_t)mt << 12) + (ks << 9));
      }
#pragma unroll
      for (int nt = 0; nt < 2; ++nt) {
        int fo = ((2 * w + nt) << 12) + (ks << 9) + (lane << 3);
        b0f[nt] = *reinterpret_cast<const bf16x8*>(wb0 + fo);
        b2f[nt] = *reinterpret_cast<const bf16x8*>(wb2 + fo);
      }
#pragma unroll
      for (int mt = 0; mt < 2; ++mt)
#pragma unroll
        for (int nt = 0; nt < 2; ++nt) {
          acc0[mt][nt] = __builtin_amdgcn_mfma_f32_16x16x32_bf16(aR[mt], b0f[nt], acc0[mt][nt], 0, 0, 0);
          acc1[mt][nt] = __builtin_amdgcn_mfma_f32_16x16x32_bf16(aP[mt], b2f[nt], acc1[mt][nt], 0, 0, 0);
        }
    }

    // ---- relu(net) -> LDS (C layout: row=(lane>>4)*4+r4, col=lane&15) ----
#pragma unroll
    for (int mt = 0; mt < 2; ++mt)
#pragma unroll
      for (int nt = 0; nt < 2; ++nt)
#pragma unroll
        for (int r4 = 0; r4 < 4; ++r4)
          snet[mt * 16 + lh4 * 4 + r4][(2 * w + nt) * 16 + l15] =
              f2bf(fmaxf(acc0[mt][nt][r4], 0.f));
    __syncthreads();

    // ---- layer 1 ----
#pragma unroll
    for (int ks = 0; ks < 4; ++ks) {
      bf16x8 b1f[2];
#pragma unroll
      for (int nt = 0; nt < 2; ++nt)
        b1f[nt] = *reinterpret_cast<const bf16x8*>(wb1 + ((2 * w + nt) << 11) + (ks << 9) + (lane << 3));
#pragma unroll
      for (int mt = 0; mt < 2; ++mt) {
        bf16x8 aS = *reinterpret_cast<const bf16x8*>(&snet[mt * 16 + l15][ks * 32 + lh4 * 8]);
#pragma unroll
        for (int nt = 0; nt < 2; ++nt)
          acc1[mt][nt] = __builtin_amdgcn_mfma_f32_16x16x32_bf16(aS, b1f[nt], acc1[mt][nt], 0, 0, 0);
      }
    }

    // ---- store ----
#pragma unroll
    for (int mt = 0; mt < 2; ++mt)
#pragma unroll
      for (int r4 = 0; r4 < 4; ++r4) {
        int row = mt * 16 + lh4 * 4 + r4;
        int pt = __shfl(ptv, row);
        if (pt >= 0) {
#pragma unroll
          for (int nt = 0; nt < 2; ++nt)
            out[(size_t)pt * SOUT + (2 * w + nt) * 16 + l15] = acc1[mt][nt][r4];
        }
      }
  }
}

// ---------------- launch ----------------

extern "C" void kernel_launch(void* const* d_in, const int* in_sizes, int n_in,
                              void* d_out, int out_size, void* d_ws, size_t ws_size,
                              hipStream_t stream) {
  const float* kls0  = (const float*)d_in[0];
  const float* kls1  = (const float*)d_in[1];
  const float* kls2  = (const float*)d_in[2];
  const float* bias0 = (const float*)d_in[3];
  const float* bias1 = (const float*)d_in[4];
  const float* x     = (const float*)d_in[5];
  const int*   bidx  = (const int*)d_in[6];
  float* out = (float*)d_out;

  int*   partial = (int*)((char*)d_ws + WS_PARTIAL);
  int*   offsets = (int*)((char*)d_ws + WS_OFFSETS);
  int*   slotmap = (int*)((char*)d_ws + WS_SLOTMAP);
  short* wb      = (short*)((char*)d_ws + WS_WBF16);
  short* xg      = (short*)((char*)d_ws + WS_XG);

  prep_kernel<<<64 + CONV_BLOCKS, 256, 0, stream>>>(
      bidx, kls0, kls1, kls2, partial, wb);
  scatter_kernel<<<64, 256, 0, stream>>>(bidx, partial, offsets, slotmap);
  xgather_kernel<<<XSLOTS / 32, 256, 0, stream>>>(x, slotmap, xg);
  fused_kernel<<<768, 256, 0, stream>>>(bias0, bias1, offsets, slotmap, wb, xg, out);
}

// Round 9
// 37.406 us; speedup vs baseline: 1.6394x; 1.6394x over previous
//
#include <hip/hip_runtime.h>

#define NSCENE 64
#define NPTS   16384
#define SIN    256
#define SH     128
#define SOUT   128
#define XSLOTS 18432              // >= NPTS + 64*31, multiple of 32

// ---- workspace layout (bytes) ----
#define WS_PARTIAL 0                          // 64*64 int
#define WS_OFFSETS 16384                      // 65 int (padded scene offsets)
#define WS_SLOTMAP 17408                      // XSLOTS ints = 73728 B
#define WS_WBF16   (17408 + 73728)            // 5,242,880 shorts (fragment-ordered)
#define WS_XG      (WS_WBF16 + 10485760)      // 2 * XR_ELEMS shorts
#define W0_ELEMS   (NSCENE*SH*SIN)            // 2,097,152
#define W1_ELEMS   (NSCENE*SOUT*SH)           // 1,048,576
#define W2_ELEMS   (NSCENE*SOUT*SIN)          // 2,097,152
#define WTOT       (W0_ELEMS+W1_ELEMS+W2_ELEMS)
#define CONV_BLOCKS (WTOT/2048)
#define XR_ELEMS   (XSLOTS * 256)             // shorts per variant
// weight fragment order per scene region: [colgrp16][ks][lane][8]
//   L0/L2: cg<<12 | ks<<9 | lane<<3 (8 ks)    L1: cg<<11 | ks<<9 | lane<<3 (4 ks)
// x fragment order: [slotgrp16][ks][lane][8]; lane = (slot&15) + 16*h4 holds
//   x[n][ks*32 + h4*8 .. +8]  (exact A-fragment layout for mfma 16x16x32)

typedef __attribute__((ext_vector_type(8))) short bf16x8;
typedef __attribute__((ext_vector_type(4))) float f32x4;

__device__ __forceinline__ short f2bf(float f) {
  unsigned int u = __float_as_uint(f);
  unsigned int r = (u + 0x7FFFu + ((u >> 16) & 1u)) >> 16;
  return (short)(r & 0xFFFFu);
}

__device__ __forceinline__ bf16x8 cvt8(const float* src) {
  float4 u0 = *reinterpret_cast<const float4*>(src);
  float4 u1 = *reinterpret_cast<const float4*>(src + 4);
  return (bf16x8){f2bf(u0.x), f2bf(u0.y), f2bf(u0.z), f2bf(u0.w),
                  f2bf(u1.x), f2bf(u1.y), f2bf(u1.z), f2bf(u1.w)};
}

// ---------------- K1: partial histograms + fragment-ordered weight conversion ----------------

__global__ __launch_bounds__(256) void prep_kernel(
    const int* __restrict__ bidx,
    const float* __restrict__ kls0, const float* __restrict__ kls1,
    const float* __restrict__ kls2,
    int* __restrict__ partial, short* __restrict__ wb)
{
  int b = blockIdx.x;
  int tid = threadIdx.x;
  if (b < 64) {
    __shared__ int lh[NSCENE];
    if (tid < NSCENE) lh[tid] = 0;
    __syncthreads();
    atomicAdd(&lh[bidx[b * 256 + tid]], 1);
    __syncthreads();
    if (tid < NSCENE) partial[b * 64 + tid] = lh[tid];
  } else {
    int e = ((b - 64) * 256 + tid) * 8;
    if (e < WTOT) {
      const float* src;
      if (e < W0_ELEMS) {
        int s = e >> 15, r = e & 32767;
        int cg = r >> 12, ks = (r >> 9) & 7, l = (r >> 3) & 63;
        int row = cg * 16 + (l & 15), k = ks * 32 + (l >> 4) * 8;
        src = kls0 + ((size_t)s << 15) + row * SIN + k;
      } else if (e < W0_ELEMS + W1_ELEMS) {
        int e1 = e - W0_ELEMS;
        int s = e1 >> 14, r = e1 & 16383;
        int cg = r >> 11, ks = (r >> 9) & 3, l = (r >> 3) & 63;
        int row = cg * 16 + (l & 15), k = ks * 32 + (l >> 4) * 8;
        src = kls1 + ((size_t)s << 14) + row * SH + k;
      } else {
        int e2 = e - W0_ELEMS - W1_ELEMS;
        int s = e2 >> 15, r = e2 & 32767;
        int cg = r >> 12, ks = (r >> 9) & 7, l = (r >> 3) & 63;
        int row = cg * 16 + (l & 15), k = ks * 32 + (l >> 4) * 8;
        src = kls2 + ((size_t)s << 15) + row * SIN + k;
      }
      *reinterpret_cast<bf16x8*>(wb + e) = cvt8(src);
    }
  }
}

// ---------------- K2: scan (padded to 32) + scatter into slotmap (R8-proven) ----------------

__global__ __launch_bounds__(256) void scatter_kernel(
    const int* __restrict__ bidx, const int* __restrict__ partial,
    int* __restrict__ offsets, int* __restrict__ slotmap)
{
  __shared__ int cur[NSCENE];
  __shared__ int scnt[NSCENE], soff[NSCENE];
  int b = blockIdx.x;
  int tid = threadIdx.x;
  if (tid < 64) {
    int s = tid;
    int colpre = 0, total = 0;
    for (int bb = 0; bb < 64; ++bb) {
      int v = partial[bb * 64 + s];
      if (bb < b) colpre += v;
      total += v;
    }
    int p = (total + 31) & ~31;
    int v = p;
    for (int off = 1; off < 64; off <<= 1) {
      int t = __shfl_up(v, off);
      if (s >= off) v += t;
    }
    int offp = v - p;
    cur[s]  = offp + colpre;
    scnt[s] = total;
    soff[s] = offp;
    if (b == 0) {
      offsets[s] = offp;
      if (s == 63) offsets[64] = v;
    }
  }
  __syncthreads();
  if (b == 0 && tid < 64) {
    int st = soff[tid] + scnt[tid];
    int en = soff[tid] + ((scnt[tid] + 31) & ~31);
    for (int i = st; i < en; ++i) slotmap[i] = -1;
  }
  int n = b * 256 + tid;
  int s2 = bidx[n];
  int pos = atomicAdd(&cur[s2], 1);
  slotmap[pos] = n;
}

// ---------------- K3: x gather + bf16 convert into A-fragment order (R8-proven) ----------------

__global__ __launch_bounds__(256) void xgather_kernel(
    const float* __restrict__ x, const int* __restrict__ slotmap,
    short* __restrict__ xg)
{
  int slot = blockIdx.x * 32 + (threadIdx.x >> 3);
  int ks   = threadIdx.x & 7;
  int n = slotmap[slot];
  if ((unsigned)n >= (unsigned)NPTS) return;   // pad (-1) or unused slot
  const float* px = x + (size_t)n * SIN + ks * 32;
  size_t fo = ((size_t)(slot >> 4) << 12) + (ks << 9) + ((slot & 15) << 3);
  short* xr = xg + fo;
  short* xp = xg + XR_ELEMS + fo;
#pragma unroll
  for (int h4 = 0; h4 < 4; ++h4) {
    float4 u0 = *reinterpret_cast<const float4*>(px + h4 * 8);
    float4 u1 = *reinterpret_cast<const float4*>(px + h4 * 8 + 4);
    bf16x8 vp = (bf16x8){f2bf(u0.x), f2bf(u0.y), f2bf(u0.z), f2bf(u0.w),
                         f2bf(u1.x), f2bf(u1.y), f2bf(u1.z), f2bf(u1.w)};
    bf16x8 vr = (bf16x8){f2bf(fmaxf(u0.x, 0.f)), f2bf(fmaxf(u0.y, 0.f)),
                         f2bf(fmaxf(u0.z, 0.f)), f2bf(fmaxf(u0.w, 0.f)),
                         f2bf(fmaxf(u1.x, 0.f)), f2bf(fmaxf(u1.y, 0.f)),
                         f2bf(fmaxf(u1.z, 0.f)), f2bf(fmaxf(u1.w, 0.f))};
    *reinterpret_cast<bf16x8*>(xp + h4 * 128) = vp;
    *reinterpret_cast<bf16x8*>(xr + h4 * 128) = vr;
  }
}

// ---------------- K4: fused GEMM — LDS-shared A (linear stage), no f2bf, no spills ----------
// grid 512: bid = t0*64 + s (scene pinned to XCD bid%8 == s%8).
// 512 threads = 8 waves; wave w owns cols [w*16, w*16+16), tile = 32 slots.

__global__ __launch_bounds__(512) void fused_kernel(
    const float* __restrict__ bias0, const float* __restrict__ bias1,
    const int* __restrict__ offsets, const int* __restrict__ slotmap,
    const short* __restrict__ wb, const short* __restrict__ xg,
    float* __restrict__ out)
{
  __shared__ __align__(16) short ldsA[16384];           // 32 KB: [var][mt][ks][lane*8]
  __shared__ __align__(16) short snet[32][SH + 8];      // 8.5 KB

  const int s    = blockIdx.x & 63;
  const int t0   = blockIdx.x >> 6;
  const int base = offsets[s];
  const int cntp = offsets[s + 1] - base;               // padded, multiple of 32
  const int tid  = threadIdx.x;
  const int lane = tid & 63;
  const int w    = tid >> 6;                            // 0..7
  const int l15  = lane & 15;
  const int lh4  = lane >> 4;
  const int col  = w * 16 + l15;

  const short* wb0 = wb + ((size_t)s << 15) + (w << 12) + (lane << 3);
  const short* wb1 = wb + W0_ELEMS + ((size_t)s << 14) + (w << 11) + (lane << 3);
  const short* wb2 = wb + W0_ELEMS + W1_ELEMS + ((size_t)s << 15) + (w << 12) + (lane << 3);

  const float bv0 = bias0[(size_t)s * SH + col];
  const float bv1 = bias1[(size_t)s * SOUT + col];

  // W1 fragments: tile-invariant, 16 VGPRs
  bf16x8 b1c[4];
#pragma unroll
  for (int ks = 0; ks < 4; ++ks)
    b1c[ks] = *reinterpret_cast<const bf16x8*>(wb1 + (ks << 9));

  for (int t = t0; t * 32 < cntp; t += 8) {
    const int p0 = base + t * 32;                       // 32-aligned
    int ptv = slotmap[p0 + (lane & 31)];                // for store mapping only
    __syncthreads();   // protect LDS reuse across tile iterations

    // ---- stage A: linear 32 KB copy (xg already in fragment order) ----
    {
      const size_t cb = ((size_t)(p0 >> 4) << 12);      // shorts; 2 mt-chunks contiguous
      bf16x8 v0 = *reinterpret_cast<const bf16x8*>(xg + cb + tid * 8);
      bf16x8 v1 = *reinterpret_cast<const bf16x8*>(xg + cb + 4096 + tid * 8);
      bf16x8 v2 = *reinterpret_cast<const bf16x8*>(xg + XR_ELEMS + cb + tid * 8);
      bf16x8 v3 = *reinterpret_cast<const bf16x8*>(xg + XR_ELEMS + cb + 4096 + tid * 8);
      *reinterpret_cast<bf16x8*>(&ldsA[tid * 8])         = v0;  // var0 (relu) mt0
      *reinterpret_cast<bf16x8*>(&ldsA[4096 + tid * 8])  = v1;  // var0 mt1
      *reinterpret_cast<bf16x8*>(&ldsA[8192 + tid * 8])  = v2;  // var1 (x)  mt0
      *reinterpret_cast<bf16x8*>(&ldsA[12288 + tid * 8]) = v3;  // var1 mt1
    }
    __syncthreads();

    // ---- layers 0 + 2: LDS A, global B (L2-resident), MFMA ----
    f32x4 acc0[2], acc1[2];
#pragma unroll
    for (int mt = 0; mt < 2; ++mt) {
      acc0[mt] = (f32x4){bv0, bv0, bv0, bv0};
      acc1[mt] = (f32x4){bv1, bv1, bv1, bv1};
    }
#pragma unroll
    for (int ks = 0; ks < 8; ++ks) {
      bf16x8 b0f = *reinterpret_cast<const bf16x8*>(wb0 + (ks << 9));
      bf16x8 b2f = *reinterpret_cast<const bf16x8*>(wb2 + (ks << 9));
#pragma unroll
      for (int mt = 0; mt < 2; ++mt) {
        bf16x8 aR = *reinterpret_cast<const bf16x8*>(&ldsA[mt * 4096 + ks * 512 + lane * 8]);
        bf16x8 aP = *reinterpret_cast<const bf16x8*>(&ldsA[8192 + mt * 4096 + ks * 512 + lane * 8]);
        acc0[mt] = __builtin_amdgcn_mfma_f32_16x16x32_bf16(aR, b0f, acc0[mt], 0, 0, 0);
        acc1[mt] = __builtin_amdgcn_mfma_f32_16x16x32_bf16(aP, b2f, acc1[mt], 0, 0, 0);
      }
    }

    // ---- relu(net) -> LDS (C layout: row=(lane>>4)*4+r4, col=lane&15) ----
#pragma unroll
    for (int mt = 0; mt < 2; ++mt)
#pragma unroll
      for (int r4 = 0; r4 < 4; ++r4)
        snet[mt * 16 + lh4 * 4 + r4][col] = f2bf(fmaxf(acc0[mt][r4], 0.f));
    __syncthreads();

    // ---- layer 1: W1 already in registers ----
#pragma unroll
    for (int ks = 0; ks < 4; ++ks) {
      int kc = ks * 32 + lh4 * 8;
#pragma unroll
      for (int mt = 0; mt < 2; ++mt) {
        bf16x8 aS = *reinterpret_cast<const bf16x8*>(&snet[mt * 16 + l15][kc]);
        acc1[mt] = __builtin_amdgcn_mfma_f32_16x16x32_bf16(aS, b1c[ks], acc1[mt], 0, 0, 0);
      }
    }

    // ---- store ----
#pragma unroll
    for (int mt = 0; mt < 2; ++mt)
#pragma unroll
      for (int r4 = 0; r4 < 4; ++r4) {
        int row = mt * 16 + lh4 * 4 + r4;
        int pt = __shfl(ptv, row);
        if (pt >= 0) out[(size_t)pt * SOUT + col] = acc1[mt][r4];
      }
  }
}

// ---------------- launch ----------------

extern "C" void kernel_launch(void* const* d_in, const int* in_sizes, int n_in,
                              void* d_out, int out_size, void* d_ws, size_t ws_size,
                              hipStream_t stream) {
  const float* kls0  = (const float*)d_in[0];
  const float* kls1  = (const float*)d_in[1];
  const float* kls2  = (const float*)d_in[2];
  const float* bias0 = (const float*)d_in[3];
  const float* bias1 = (const float*)d_in[4];
  const float* x     = (const float*)d_in[5];
  const int*   bidx  = (const int*)d_in[6];
  float* out = (float*)d_out;

  int*   partial = (int*)((char*)d_ws + WS_PARTIAL);
  int*   offsets = (int*)((char*)d_ws + WS_OFFSETS);
  int*   slotmap = (int*)((char*)d_ws + WS_SLOTMAP);
  short* wb      = (short*)((char*)d_ws + WS_WBF16);
  short* xg      = (short*)((char*)d_ws + WS_XG);

  prep_kernel<<<64 + CONV_BLOCKS, 256, 0, stream>>>(
      bidx, kls0, kls1, kls2, partial, wb);
  scatter_kernel<<<64, 256, 0, stream>>>(bidx, partial, offsets, slotmap);
  xgather_kernel<<<XSLOTS / 32, 256, 0, stream>>>(x, slotmap, xg);
  fused_kernel<<<512, 512, 0, stream>>>(bias0, bias1, offsets, slotmap, wb, xg, out);
}

// Round 10
// 37.306 us; speedup vs baseline: 1.6438x; 1.0027x over previous
//
#include <hip/hip_runtime.h>

#define NSCENE 64
#define NPTS   16384
#define SIN    256
#define SH     128
#define SOUT   128
#define XSLOTS 18432              // >= NPTS + 64*31, multiple of 32

// ---- workspace layout (bytes) ----
#define WS_PARTIAL 0                          // 64*64 int
#define WS_OFFSETS 16384                      // 65 int (padded scene offsets)
#define WS_SLOTMAP 17408                      // XSLOTS ints = 73728 B
#define WS_WBF16   (17408 + 73728)            // 5,242,880 shorts (fragment-ordered)
#define WS_XG      (WS_WBF16 + 10485760)      // 2 * XR_ELEMS shorts
#define W0_ELEMS   (NSCENE*SH*SIN)            // 2,097,152
#define W1_ELEMS   (NSCENE*SOUT*SH)           // 1,048,576
#define W2_ELEMS   (NSCENE*SOUT*SIN)          // 2,097,152
#define WTOT       (W0_ELEMS+W1_ELEMS+W2_ELEMS)
#define CONV_BLOCKS (WTOT/2048)
#define XR_ELEMS   (XSLOTS * 256)             // shorts per variant
// weight fragment order per scene region: [colgrp16][ks][lane][8]
//   L0/L2: cg<<12 | ks<<9 | lane<<3 (8 ks)    L1: cg<<11 | ks<<9 | lane<<3 (4 ks)
// x fragment order: [slotgrp16][ks][lane][8]; lane = (slot&15) + 16*h4 holds
//   x[n][ks*32 + h4*8 .. +8]  (exact A-fragment layout for mfma 16x16x32)

typedef __attribute__((ext_vector_type(8))) short bf16x8;
typedef __attribute__((ext_vector_type(4))) float f32x4;

__device__ __forceinline__ short f2bf(float f) {
  unsigned int u = __float_as_uint(f);
  unsigned int r = (u + 0x7FFFu + ((u >> 16) & 1u)) >> 16;
  return (short)(r & 0xFFFFu);
}

__device__ __forceinline__ bf16x8 cvt8(const float* src) {
  float4 u0 = *reinterpret_cast<const float4*>(src);
  float4 u1 = *reinterpret_cast<const float4*>(src + 4);
  return (bf16x8){f2bf(u0.x), f2bf(u0.y), f2bf(u0.z), f2bf(u0.w),
                  f2bf(u1.x), f2bf(u1.y), f2bf(u1.z), f2bf(u1.w)};
}

// ---------------- K1: partial histograms + fragment-ordered weight conversion ----------------

__global__ __launch_bounds__(256) void prep_kernel(
    const int* __restrict__ bidx,
    const float* __restrict__ kls0, const float* __restrict__ kls1,
    const float* __restrict__ kls2,
    int* __restrict__ partial, short* __restrict__ wb)
{
  int b = blockIdx.x;
  int tid = threadIdx.x;
  if (b < 64) {
    __shared__ int lh[NSCENE];
    if (tid < NSCENE) lh[tid] = 0;
    __syncthreads();
    atomicAdd(&lh[bidx[b * 256 + tid]], 1);
    __syncthreads();
    if (tid < NSCENE) partial[b * 64 + tid] = lh[tid];
  } else {
    int e = ((b - 64) * 256 + tid) * 8;
    if (e < WTOT) {
      const float* src;
      if (e < W0_ELEMS) {
        int s = e >> 15, r = e & 32767;
        int cg = r >> 12, ks = (r >> 9) & 7, l = (r >> 3) & 63;
        int row = cg * 16 + (l & 15), k = ks * 32 + (l >> 4) * 8;
        src = kls0 + ((size_t)s << 15) + row * SIN + k;
      } else if (e < W0_ELEMS + W1_ELEMS) {
        int e1 = e - W0_ELEMS;
        int s = e1 >> 14, r = e1 & 16383;
        int cg = r >> 11, ks = (r >> 9) & 3, l = (r >> 3) & 63;
        int row = cg * 16 + (l & 15), k = ks * 32 + (l >> 4) * 8;
        src = kls1 + ((size_t)s << 14) + row * SH + k;
      } else {
        int e2 = e - W0_ELEMS - W1_ELEMS;
        int s = e2 >> 15, r = e2 & 32767;
        int cg = r >> 12, ks = (r >> 9) & 7, l = (r >> 3) & 63;
        int row = cg * 16 + (l & 15), k = ks * 32 + (l >> 4) * 8;
        src = kls2 + ((size_t)s << 15) + row * SIN + k;
      }
      *reinterpret_cast<bf16x8*>(wb + e) = cvt8(src);
    }
  }
}

// ---------------- K2: scan (padded to 32) + scatter into slotmap (R8-proven) ----------------

__global__ __launch_bounds__(256) void scatter_kernel(
    const int* __restrict__ bidx, const int* __restrict__ partial,
    int* __restrict__ offsets, int* __restrict__ slotmap)
{
  __shared__ int cur[NSCENE];
  __shared__ int scnt[NSCENE], soff[NSCENE];
  int b = blockIdx.x;
  int tid = threadIdx.x;
  if (tid < 64) {
    int s = tid;
    int colpre = 0, total = 0;
    for (int bb = 0; bb < 64; ++bb) {
      int v = partial[bb * 64 + s];
      if (bb < b) colpre += v;
      total += v;
    }
    int p = (total + 31) & ~31;
    int v = p;
    for (int off = 1; off < 64; off <<= 1) {
      int t = __shfl_up(v, off);
      if (s >= off) v += t;
    }
    int offp = v - p;
    cur[s]  = offp + colpre;
    scnt[s] = total;
    soff[s] = offp;
    if (b == 0) {
      offsets[s] = offp;
      if (s == 63) offsets[64] = v;
    }
  }
  __syncthreads();
  if (b == 0 && tid < 64) {
    int st = soff[tid] + scnt[tid];
    int en = soff[tid] + ((scnt[tid] + 31) & ~31);
    for (int i = st; i < en; ++i) slotmap[i] = -1;
  }
  int n = b * 256 + tid;
  int s2 = bidx[n];
  int pos = atomicAdd(&cur[s2], 1);
  slotmap[pos] = n;
}

// ---------------- K3: x gather + bf16 convert into A-fragment order (R8-proven) ----------------

__global__ __launch_bounds__(256) void xgather_kernel(
    const float* __restrict__ x, const int* __restrict__ slotmap,
    short* __restrict__ xg)
{
  int slot = blockIdx.x * 32 + (threadIdx.x >> 3);
  int ks   = threadIdx.x & 7;
  int n = slotmap[slot];
  if ((unsigned)n >= (unsigned)NPTS) return;   // pad (-1) or unused slot
  const float* px = x + (size_t)n * SIN + ks * 32;
  size_t fo = ((size_t)(slot >> 4) << 12) + (ks << 9) + ((slot & 15) << 3);
  short* xr = xg + fo;
  short* xp = xg + XR_ELEMS + fo;
#pragma unroll
  for (int h4 = 0; h4 < 4; ++h4) {
    float4 u0 = *reinterpret_cast<const float4*>(px + h4 * 8);
    float4 u1 = *reinterpret_cast<const float4*>(px + h4 * 8 + 4);
    bf16x8 vp = (bf16x8){f2bf(u0.x), f2bf(u0.y), f2bf(u0.z), f2bf(u0.w),
                         f2bf(u1.x), f2bf(u1.y), f2bf(u1.z), f2bf(u1.w)};
    bf16x8 vr = (bf16x8){f2bf(fmaxf(u0.x, 0.f)), f2bf(fmaxf(u0.y, 0.f)),
                         f2bf(fmaxf(u0.z, 0.f)), f2bf(fmaxf(u0.w, 0.f)),
                         f2bf(fmaxf(u1.x, 0.f)), f2bf(fmaxf(u1.y, 0.f)),
                         f2bf(fmaxf(u1.z, 0.f)), f2bf(fmaxf(u1.w, 0.f))};
    *reinterpret_cast<bf16x8*>(xp + h4 * 128) = vp;
    *reinterpret_cast<bf16x8*>(xr + h4 * 128) = vr;
  }
}

// ---------------- K4: fused GEMM — LDS-shared A (linear stage), no f2bf, no spills ----------
// grid 512: bid = t0*64 + s (scene pinned to XCD bid%8 == s%8).
// 512 threads = 8 waves; wave w owns cols [w*16, w*16+16), tile = 32 slots.

__global__ __launch_bounds__(512) void fused_kernel(
    const float* __restrict__ bias0, const float* __restrict__ bias1,
    const int* __restrict__ offsets, const int* __restrict__ slotmap,
    const short* __restrict__ wb, const short* __restrict__ xg,
    float* __restrict__ out)
{
  __shared__ __align__(16) short ldsA[16384];           // 32 KB: [var][mt][ks][lane*8]
  __shared__ __align__(16) short snet[32][SH + 8];      // 8.5 KB

  const int s    = blockIdx.x & 63;
  const int t0   = blockIdx.x >> 6;
  const int base = offsets[s];
  const int cntp = offsets[s + 1] - base;               // padded, multiple of 32
  const int tid  = threadIdx.x;
  const int lane = tid & 63;
  const int w    = tid >> 6;                            // 0..7
  const int l15  = lane & 15;
  const int lh4  = lane >> 4;
  const int col  = w * 16 + l15;

  const short* wb0 = wb + ((size_t)s << 15) + (w << 12) + (lane << 3);
  const short* wb1 = wb + W0_ELEMS + ((size_t)s << 14) + (w << 11) + (lane << 3);
  const short* wb2 = wb + W0_ELEMS + W1_ELEMS + ((size_t)s << 15) + (w << 12) + (lane << 3);

  const float bv0 = bias0[(size_t)s * SH + col];
  const float bv1 = bias1[(size_t)s * SOUT + col];

  // W1 fragments: tile-invariant, 16 VGPRs
  bf16x8 b1c[4];
#pragma unroll
  for (int ks = 0; ks < 4; ++ks)
    b1c[ks] = *reinterpret_cast<const bf16x8*>(wb1 + (ks << 9));

  for (int t = t0; t * 32 < cntp; t += 8) {
    const int p0 = base + t * 32;                       // 32-aligned
    int ptv = slotmap[p0 + (lane & 31)];                // for store mapping only
    __syncthreads();   // protect LDS reuse across tile iterations

    // ---- stage A: linear 32 KB copy (xg already in fragment order) ----
    {
      const size_t cb = ((size_t)(p0 >> 4) << 12);      // shorts; 2 mt-chunks contiguous
      bf16x8 v0 = *reinterpret_cast<const bf16x8*>(xg + cb + tid * 8);
      bf16x8 v1 = *reinterpret_cast<const bf16x8*>(xg + cb + 4096 + tid * 8);
      bf16x8 v2 = *reinterpret_cast<const bf16x8*>(xg + XR_ELEMS + cb + tid * 8);
      bf16x8 v3 = *reinterpret_cast<const bf16x8*>(xg + XR_ELEMS + cb + 4096 + tid * 8);
      *reinterpret_cast<bf16x8*>(&ldsA[tid * 8])         = v0;  // var0 (relu) mt0
      *reinterpret_cast<bf16x8*>(&ldsA[4096 + tid * 8])  = v1;  // var0 mt1
      *reinterpret_cast<bf16x8*>(&ldsA[8192 + tid * 8])  = v2;  // var1 (x)  mt0
      *reinterpret_cast<bf16x8*>(&ldsA[12288 + tid * 8]) = v3;  // var1 mt1
    }
    __syncthreads();

    // ---- layers 0 + 2: LDS A, global B (L2-resident), MFMA ----
    f32x4 acc0[2], acc1[2];
#pragma unroll
    for (int mt = 0; mt < 2; ++mt) {
      acc0[mt] = (f32x4){bv0, bv0, bv0, bv0};
      acc1[mt] = (f32x4){bv1, bv1, bv1, bv1};
    }
#pragma unroll
    for (int ks = 0; ks < 8; ++ks) {
      bf16x8 b0f = *reinterpret_cast<const bf16x8*>(wb0 + (ks << 9));
      bf16x8 b2f = *reinterpret_cast<const bf16x8*>(wb2 + (ks << 9));
#pragma unroll
      for (int mt = 0; mt < 2; ++mt) {
        bf16x8 aR = *reinterpret_cast<const bf16x8*>(&ldsA[mt * 4096 + ks * 512 + lane * 8]);
        bf16x8 aP = *reinterpret_cast<const bf16x8*>(&ldsA[8192 + mt * 4096 + ks * 512 + lane * 8]);
        acc0[mt] = __builtin_amdgcn_mfma_f32_16x16x32_bf16(aR, b0f, acc0[mt], 0, 0, 0);
        acc1[mt] = __builtin_amdgcn_mfma_f32_16x16x32_bf16(aP, b2f, acc1[mt], 0, 0, 0);
      }
    }

    // ---- relu(net) -> LDS (C layout: row=(lane>>4)*4+r4, col=lane&15) ----
#pragma unroll
    for (int mt = 0; mt < 2; ++mt)
#pragma unroll
      for (int r4 = 0; r4 < 4; ++r4)
        snet[mt * 16 + lh4 * 4 + r4][col] = f2bf(fmaxf(acc0[mt][r4], 0.f));
    __syncthreads();

    // ---- layer 1: W1 already in registers ----
#pragma unroll
    for (int ks = 0; ks < 4; ++ks) {
      int kc = ks * 32 + lh4 * 8;
#pragma unroll
      for (int mt = 0; mt < 2; ++mt) {
        bf16x8 aS = *reinterpret_cast<const bf16x8*>(&snet[mt * 16 + l15][kc]);
        acc1[mt] = __builtin_amdgcn_mfma_f32_16x16x32_bf16(aS, b1c[ks], acc1[mt], 0, 0, 0);
      }
    }

    // ---- store ----
#pragma unroll
    for (int mt = 0; mt < 2; ++mt)
#pragma unroll
      for (int r4 = 0; r4 < 4; ++r4) {
        int row = mt * 16 + lh4 * 4 + r4;
        int pt = __shfl(ptv, row);
        if (pt >= 0) out[(size_t)pt * SOUT + col] = acc1[mt][r4];
      }
  }
}

// ---------------- launch ----------------

extern "C" void kernel_launch(void* const* d_in, const int* in_sizes, int n_in,
                              void* d_out, int out_size, void* d_ws, size_t ws_size,
                              hipStream_t stream) {
  const float* kls0  = (const float*)d_in[0];
  const float* kls1  = (const float*)d_in[1];
  const float* kls2  = (const float*)d_in[2];
  const float* bias0 = (const float*)d_in[3];
  const float* bias1 = (const float*)d_in[4];
  const float* x     = (const float*)d_in[5];
  const int*   bidx  = (const int*)d_in[6];
  float* out = (float*)d_out;

  int*   partial = (int*)((char*)d_ws + WS_PARTIAL);
  int*   offsets = (int*)((char*)d_ws + WS_OFFSETS);
  int*   slotmap = (int*)((char*)d_ws + WS_SLOTMAP);
  short* wb      = (short*)((char*)d_ws + WS_WBF16);
  short* xg      = (short*)((char*)d_ws + WS_XG);

  prep_kernel<<<64 + CONV_BLOCKS, 256, 0, stream>>>(
      bidx, kls0, kls1, kls2, partial, wb);
  scatter_kernel<<<64, 256, 0, stream>>>(bidx, partial, offsets, slotmap);
  xgather_kernel<<<XSLOTS / 32, 256, 0, stream>>>(x, slotmap, xg);
  fused_kernel<<<512, 512, 0, stream>>>(bias0, bias1, offsets, slotmap, wb, xg, out);
}